// Round 9
// baseline (1055.587 us; speedup 1.0000x reference)
//
#include <hip/hip_runtime.h>

// SimpleAttention v9: v5 geometry (TT=32, 1024 thr, 128KB p-LDS) + ping-pong
// depth-1 ctx prefetch in phase B (branch-free, statically-indexed buffers).
// out[b, i*64+d, t] = sum_j softmax_j(a[i][j]) * ctx[j][d]   (per b,t)
// attentions[b,i,j,t] = p[j] + (i==j ? 0 : p[j+32])

typedef unsigned int uint_t;

constexpr int Bq = 16, Cq = 3072, Tq = 2048;
constexpr int TT = 32;                   // t-tile = one 128B line
constexpr int TILES = Tq / TT;           // 64
constexpr int NBLK = Bq * TILES;         // 1024
constexpr size_t ATT_OFF = (size_t)Bq * 2048 * Tq;

__global__ __launch_bounds__(1024, 4) void attn_v9(const float* __restrict__ x,
                                                   const float* __restrict__ xi,
                                                   float* __restrict__ out)
{
    // p packed bf16 pairs: word k holds (p[2k], p[2k+1]) for row i, time tl.
    // word-index = k*1024 + tl*32 + (i ^ ((tl&7)<<2))   -> 128 KB
    __shared__ uint_t plds[32 * 32 * 32];

    const int b    = (int)blockIdx.x >> 6;
    const int tile = (int)blockIdx.x & (TILES - 1);
    const int t0   = tile * TT;
    const int tl   = (int)threadIdx.x & 31;
    const int slot = (int)threadIdx.x >> 5;      // 0..31
    const int xw   = (tl & 7) << 2;              // word-index XOR swizzle

    const float* xb  = x  + (size_t)b * Cq * Tq + t0 + tl;
    const float* xib = xi + (size_t)b * Cq * Tq + t0 + tl;

    // ---- phase A: softmax for row i = slot; attn out; p -> LDS ----
    {
        const int i = slot;
        float p[64];
#pragma unroll
        for (int j = 0; j < 32; ++j) p[j]      = xb [(size_t)(i * 96 + j) * Tq];
#pragma unroll
        for (int j = 0; j < 32; ++j) p[j + 32] = xib[(size_t)(i * 96 + j) * Tq];
        float m = p[0];
#pragma unroll
        for (int j = 1; j < 64; ++j) m = fmaxf(m, p[j]);
        float s = 0.f;
#pragma unroll
        for (int j = 0; j < 64; ++j) { p[j] = __expf(p[j] - m); s += p[j]; }
        const float inv = 1.f / s;
#pragma unroll
        for (int j = 0; j < 64; ++j) p[j] *= inv;

        float* ao = out + ATT_OFF + ((size_t)(b * 32 + i) * 32) * Tq + t0 + tl;
#pragma unroll
        for (int j = 0; j < 32; ++j) {
            float v = p[j] + ((j == i) ? 0.f : p[j + 32]);
            __builtin_nontemporal_store(v, &ao[(size_t)j * Tq]);
        }
#pragma unroll
        for (int k = 0; k < 32; ++k) {
            uint_t b0 = __float_as_uint(p[2 * k]);
            uint_t b1 = __float_as_uint(p[2 * k + 1]);
            uint_t lo = (b0 + 0x7fffu + ((b0 >> 16) & 1u)) >> 16;
            uint_t hi = (b1 + 0x7fffu + ((b1 >> 16) & 1u)) >> 16;
            plds[k * 1024 + tl * 32 + (i ^ xw)] = lo | (hi << 16);
        }
    }

    // ---- phase B: thread = (ig,dg,tl); acc 8i x 8d; ping-pong prefetch ----
    const int ig = slot & 3;                     // i = ig*8 + r
    const int dg = slot >> 2;                    // d = dg*8 + dd
    const int d0 = dg * 8;
    const int pbase = tl * 32;

    const float* cx  = x  + (size_t)b * Cq * Tq + (size_t)(32 + d0) * Tq + t0 + tl;
    const float* cxi = xi + (size_t)b * Cq * Tq + (size_t)(32 + d0) * Tq + t0 + tl;

    float acc[8][8];
#pragma unroll
    for (int r = 0; r < 8; ++r)
#pragma unroll
        for (int dd = 0; dd < 8; ++dd) acc[r][dd] = 0.f;

    float ca0[8], ca1[8], cb0[8], cb1[8];
    // preload k=0 (kg=0, from cx) before the barrier
#pragma unroll
    for (int dd = 0; dd < 8; ++dd) ca0[dd] = cx[(size_t)dd * Tq];
#pragma unroll
    for (int dd = 0; dd < 8; ++dd) ca1[dd] = cx[(size_t)(96 + dd) * Tq];

    __syncthreads();

    // one macro-iteration handles k=2kk (compute ca, refill cb) and
    // k=2kk+1 (compute cb, refill ca). Last refill wraps to k=0 (harmless).
    for (int kk = 0; kk < 16; ++kk) {
        // ---- k0 = 2kk: prefetch k0+1 into cb ----
        {
            const int kn = 2 * kk + 1;           // 1..31
            const float* bn = (kn < 16) ? cx : cxi;
            const int ng = kn & 15;
#pragma unroll
            for (int dd = 0; dd < 8; ++dd) cb0[dd] = bn[(size_t)(ng * 192 + dd) * Tq];
#pragma unroll
            for (int dd = 0; dd < 8; ++dd) cb1[dd] = bn[(size_t)(ng * 192 + 96 + dd) * Tq];
        }
        {
            const int k = 2 * kk;
            const uint4 wa = *reinterpret_cast<const uint4*>(
                &plds[k * 1024 + pbase + ((ig * 8 + 0) ^ xw)]);
            const uint4 wb = *reinterpret_cast<const uint4*>(
                &plds[k * 1024 + pbase + ((ig * 8 + 4) ^ xw)]);
            float pj0[8], pj1[8];
            pj0[0] = __uint_as_float(wa.x << 16);  pj1[0] = __uint_as_float(wa.x & 0xffff0000u);
            pj0[1] = __uint_as_float(wa.y << 16);  pj1[1] = __uint_as_float(wa.y & 0xffff0000u);
            pj0[2] = __uint_as_float(wa.z << 16);  pj1[2] = __uint_as_float(wa.z & 0xffff0000u);
            pj0[3] = __uint_as_float(wa.w << 16);  pj1[3] = __uint_as_float(wa.w & 0xffff0000u);
            pj0[4] = __uint_as_float(wb.x << 16);  pj1[4] = __uint_as_float(wb.x & 0xffff0000u);
            pj0[5] = __uint_as_float(wb.y << 16);  pj1[5] = __uint_as_float(wb.y & 0xffff0000u);
            pj0[6] = __uint_as_float(wb.z << 16);  pj1[6] = __uint_as_float(wb.z & 0xffff0000u);
            pj0[7] = __uint_as_float(wb.w << 16);  pj1[7] = __uint_as_float(wb.w & 0xffff0000u);
#pragma unroll
            for (int r = 0; r < 8; ++r)
#pragma unroll
                for (int dd = 0; dd < 8; ++dd)
                    acc[r][dd] += pj0[r] * ca0[dd] + pj1[r] * ca1[dd];
        }
        // ---- k1 = 2kk+1: prefetch (k1+1)&31 into ca ----
        {
            const int kn = (2 * kk + 2) & 31;    // 2..30 even, 0 at kk=15 (wrap)
            const float* bn = (kn < 16) ? cx : cxi;
            const int ng = kn & 15;
#pragma unroll
            for (int dd = 0; dd < 8; ++dd) ca0[dd] = bn[(size_t)(ng * 192 + dd) * Tq];
#pragma unroll
            for (int dd = 0; dd < 8; ++dd) ca1[dd] = bn[(size_t)(ng * 192 + 96 + dd) * Tq];
        }
        {
            const int k = 2 * kk + 1;
            const uint4 wa = *reinterpret_cast<const uint4*>(
                &plds[k * 1024 + pbase + ((ig * 8 + 0) ^ xw)]);
            const uint4 wb = *reinterpret_cast<const uint4*>(
                &plds[k * 1024 + pbase + ((ig * 8 + 4) ^ xw)]);
            float pj0[8], pj1[8];
            pj0[0] = __uint_as_float(wa.x << 16);  pj1[0] = __uint_as_float(wa.x & 0xffff0000u);
            pj0[1] = __uint_as_float(wa.y << 16);  pj1[1] = __uint_as_float(wa.y & 0xffff0000u);
            pj0[2] = __uint_as_float(wa.z << 16);  pj1[2] = __uint_as_float(wa.z & 0xffff0000u);
            pj0[3] = __uint_as_float(wa.w << 16);  pj1[3] = __uint_as_float(wa.w & 0xffff0000u);
            pj0[4] = __uint_as_float(wb.x << 16);  pj1[4] = __uint_as_float(wb.x & 0xffff0000u);
            pj0[5] = __uint_as_float(wb.y << 16);  pj1[5] = __uint_as_float(wb.y & 0xffff0000u);
            pj0[6] = __uint_as_float(wb.z << 16);  pj1[6] = __uint_as_float(wb.z & 0xffff0000u);
            pj0[7] = __uint_as_float(wb.w << 16);  pj1[7] = __uint_as_float(wb.w & 0xffff0000u);
#pragma unroll
            for (int r = 0; r < 8; ++r)
#pragma unroll
                for (int dd = 0; dd < 8; ++dd)
                    acc[r][dd] += pj0[r] * cb0[dd] + pj1[r] * cb1[dd];
        }
    }

    float* ob = out + (size_t)b * 2048 * Tq + t0 + tl;
#pragma unroll
    for (int r = 0; r < 8; ++r)
#pragma unroll
        for (int dd = 0; dd < 8; ++dd) {
            int ch = (ig * 8 + r) * 64 + d0 + dd;
            __builtin_nontemporal_store(acc[r][dd], &ob[(size_t)ch * Tq]);
        }
}

extern "C" void kernel_launch(void* const* d_in, const int* in_sizes, int n_in,
                              void* d_out, int out_size, void* d_ws, size_t ws_size,
                              hipStream_t stream) {
    const float* x  = (const float*)d_in[0];
    const float* xi = (const float*)d_in[1];
    float* out = (float*)d_out;
    attn_v9<<<dim3(NBLK), dim3(1024), 0, stream>>>(x, xi, out);
}

// Round 10
// 1053.140 us; speedup vs baseline: 1.0023x; 1.0023x over previous
//
#include <hip/hip_runtime.h>

// SimpleAttention v10: v9 ping-pong prefetch + launch_bounds(1024,1).
// NOTE [measured v3..v9]: hipcc's 2nd launch_bounds arg behaves as min
// WORKGROUPS/CU (CUDA semantics): (1024,4)->64-VGPR cap (spills!),
// (1024,1) -> 1 block/CU -> 128-VGPR cap. LDS=128KB forces 1 block/CU anyway.
// out[b, i*64+d, t] = sum_j softmax_j(a[i][j]) * ctx[j][d]   (per b,t)
// attentions[b,i,j,t] = p[j] + (i==j ? 0 : p[j+32])

typedef unsigned int uint_t;

constexpr int Bq = 16, Cq = 3072, Tq = 2048;
constexpr int TT = 32;                   // t-tile = one 128B line
constexpr int TILES = Tq / TT;           // 64
constexpr int NBLK = Bq * TILES;         // 1024
constexpr size_t ATT_OFF = (size_t)Bq * 2048 * Tq;

__global__ __launch_bounds__(1024, 1) void attn_v10(const float* __restrict__ x,
                                                    const float* __restrict__ xi,
                                                    float* __restrict__ out)
{
    // p packed bf16 pairs: word k holds (p[2k], p[2k+1]) for row i, time tl.
    // word-index = k*1024 + tl*32 + (i ^ ((tl&7)<<2))   -> 128 KB
    __shared__ uint_t plds[32 * 32 * 32];

    const int b    = (int)blockIdx.x >> 6;
    const int tile = (int)blockIdx.x & (TILES - 1);
    const int t0   = tile * TT;
    const int tl   = (int)threadIdx.x & 31;
    const int slot = (int)threadIdx.x >> 5;      // 0..31
    const int xw   = (tl & 7) << 2;              // word-index XOR swizzle

    const float* xb  = x  + (size_t)b * Cq * Tq + t0 + tl;
    const float* xib = xi + (size_t)b * Cq * Tq + t0 + tl;

    // ---- phase A: softmax for row i = slot; attn out; p -> LDS ----
    {
        const int i = slot;
        float p[64];
#pragma unroll
        for (int j = 0; j < 32; ++j) p[j]      = xb [(size_t)(i * 96 + j) * Tq];
#pragma unroll
        for (int j = 0; j < 32; ++j) p[j + 32] = xib[(size_t)(i * 96 + j) * Tq];
        float m = p[0];
#pragma unroll
        for (int j = 1; j < 64; ++j) m = fmaxf(m, p[j]);
        float s = 0.f;
#pragma unroll
        for (int j = 0; j < 64; ++j) { p[j] = __expf(p[j] - m); s += p[j]; }
        const float inv = 1.f / s;
#pragma unroll
        for (int j = 0; j < 64; ++j) p[j] *= inv;

        float* ao = out + ATT_OFF + ((size_t)(b * 32 + i) * 32) * Tq + t0 + tl;
#pragma unroll
        for (int j = 0; j < 32; ++j) {
            float v = p[j] + ((j == i) ? 0.f : p[j + 32]);
            __builtin_nontemporal_store(v, &ao[(size_t)j * Tq]);
        }
#pragma unroll
        for (int k = 0; k < 32; ++k) {
            uint_t b0 = __float_as_uint(p[2 * k]);
            uint_t b1 = __float_as_uint(p[2 * k + 1]);
            uint_t lo = (b0 + 0x7fffu + ((b0 >> 16) & 1u)) >> 16;
            uint_t hi = (b1 + 0x7fffu + ((b1 >> 16) & 1u)) >> 16;
            plds[k * 1024 + tl * 32 + (i ^ xw)] = lo | (hi << 16);
        }
    }

    // ---- phase B: thread = (ig,dg,tl); acc 8i x 8d; ping-pong prefetch ----
    const int ig = slot & 3;                     // i = ig*8 + r
    const int dg = slot >> 2;                    // d = dg*8 + dd
    const int d0 = dg * 8;
    const int pbase = tl * 32;

    const float* cx  = x  + (size_t)b * Cq * Tq + (size_t)(32 + d0) * Tq + t0 + tl;
    const float* cxi = xi + (size_t)b * Cq * Tq + (size_t)(32 + d0) * Tq + t0 + tl;

    float acc[8][8];
#pragma unroll
    for (int r = 0; r < 8; ++r)
#pragma unroll
        for (int dd = 0; dd < 8; ++dd) acc[r][dd] = 0.f;

    float ca0[8], ca1[8], cb0[8], cb1[8];
    // preload k=0 (kg=0, from cx) before the barrier
#pragma unroll
    for (int dd = 0; dd < 8; ++dd) ca0[dd] = cx[(size_t)dd * Tq];
#pragma unroll
    for (int dd = 0; dd < 8; ++dd) ca1[dd] = cx[(size_t)(96 + dd) * Tq];

    __syncthreads();

    // one macro-iteration handles k=2kk (compute ca, refill cb) and
    // k=2kk+1 (compute cb, refill ca). Last refill wraps to k=0 (harmless).
    for (int kk = 0; kk < 16; ++kk) {
        // ---- k0 = 2kk: prefetch k0+1 into cb ----
        {
            const int kn = 2 * kk + 1;           // 1..31
            const float* bn = (kn < 16) ? cx : cxi;
            const int ng = kn & 15;
#pragma unroll
            for (int dd = 0; dd < 8; ++dd) cb0[dd] = bn[(size_t)(ng * 192 + dd) * Tq];
#pragma unroll
            for (int dd = 0; dd < 8; ++dd) cb1[dd] = bn[(size_t)(ng * 192 + 96 + dd) * Tq];
        }
        {
            const int k = 2 * kk;
            const uint4 wa = *reinterpret_cast<const uint4*>(
                &plds[k * 1024 + pbase + ((ig * 8 + 0) ^ xw)]);
            const uint4 wb = *reinterpret_cast<const uint4*>(
                &plds[k * 1024 + pbase + ((ig * 8 + 4) ^ xw)]);
            float pj0[8], pj1[8];
            pj0[0] = __uint_as_float(wa.x << 16);  pj1[0] = __uint_as_float(wa.x & 0xffff0000u);
            pj0[1] = __uint_as_float(wa.y << 16);  pj1[1] = __uint_as_float(wa.y & 0xffff0000u);
            pj0[2] = __uint_as_float(wa.z << 16);  pj1[2] = __uint_as_float(wa.z & 0xffff0000u);
            pj0[3] = __uint_as_float(wa.w << 16);  pj1[3] = __uint_as_float(wa.w & 0xffff0000u);
            pj0[4] = __uint_as_float(wb.x << 16);  pj1[4] = __uint_as_float(wb.x & 0xffff0000u);
            pj0[5] = __uint_as_float(wb.y << 16);  pj1[5] = __uint_as_float(wb.y & 0xffff0000u);
            pj0[6] = __uint_as_float(wb.z << 16);  pj1[6] = __uint_as_float(wb.z & 0xffff0000u);
            pj0[7] = __uint_as_float(wb.w << 16);  pj1[7] = __uint_as_float(wb.w & 0xffff0000u);
#pragma unroll
            for (int r = 0; r < 8; ++r)
#pragma unroll
                for (int dd = 0; dd < 8; ++dd)
                    acc[r][dd] += pj0[r] * ca0[dd] + pj1[r] * ca1[dd];
        }
        // ---- k1 = 2kk+1: prefetch (k1+1)&31 into ca ----
        {
            const int kn = (2 * kk + 2) & 31;    // 2..30 even, 0 at kk=15 (wrap)
            const float* bn = (kn < 16) ? cx : cxi;
            const int ng = kn & 15;
#pragma unroll
            for (int dd = 0; dd < 8; ++dd) ca0[dd] = bn[(size_t)(ng * 192 + dd) * Tq];
#pragma unroll
            for (int dd = 0; dd < 8; ++dd) ca1[dd] = bn[(size_t)(ng * 192 + 96 + dd) * Tq];
        }
        {
            const int k = 2 * kk + 1;
            const uint4 wa = *reinterpret_cast<const uint4*>(
                &plds[k * 1024 + pbase + ((ig * 8 + 0) ^ xw)]);
            const uint4 wb = *reinterpret_cast<const uint4*>(
                &plds[k * 1024 + pbase + ((ig * 8 + 4) ^ xw)]);
            float pj0[8], pj1[8];
            pj0[0] = __uint_as_float(wa.x << 16);  pj1[0] = __uint_as_float(wa.x & 0xffff0000u);
            pj0[1] = __uint_as_float(wa.y << 16);  pj1[1] = __uint_as_float(wa.y & 0xffff0000u);
            pj0[2] = __uint_as_float(wa.z << 16);  pj1[2] = __uint_as_float(wa.z & 0xffff0000u);
            pj0[3] = __uint_as_float(wa.w << 16);  pj1[3] = __uint_as_float(wa.w & 0xffff0000u);
            pj0[4] = __uint_as_float(wb.x << 16);  pj1[4] = __uint_as_float(wb.x & 0xffff0000u);
            pj0[5] = __uint_as_float(wb.y << 16);  pj1[5] = __uint_as_float(wb.y & 0xffff0000u);
            pj0[6] = __uint_as_float(wb.z << 16);  pj1[6] = __uint_as_float(wb.z & 0xffff0000u);
            pj0[7] = __uint_as_float(wb.w << 16);  pj1[7] = __uint_as_float(wb.w & 0xffff0000u);
#pragma unroll
            for (int r = 0; r < 8; ++r)
#pragma unroll
                for (int dd = 0; dd < 8; ++dd)
                    acc[r][dd] += pj0[r] * cb0[dd] + pj1[r] * cb1[dd];
        }
    }

    float* ob = out + (size_t)b * 2048 * Tq + t0 + tl;
#pragma unroll
    for (int r = 0; r < 8; ++r)
#pragma unroll
        for (int dd = 0; dd < 8; ++dd) {
            int ch = (ig * 8 + r) * 64 + d0 + dd;
            __builtin_nontemporal_store(acc[r][dd], &ob[(size_t)ch * Tq]);
        }
}

extern "C" void kernel_launch(void* const* d_in, const int* in_sizes, int n_in,
                              void* d_out, int out_size, void* d_ws, size_t ws_size,
                              hipStream_t stream) {
    const float* x  = (const float*)d_in[0];
    const float* xi = (const float*)d_in[1];
    float* out = (float*)d_out;
    attn_v10<<<dim3(NBLK), dim3(1024), 0, stream>>>(x, xi, out);
}

// Round 12
// 270.775 us; speedup vs baseline: 3.8984x; 3.8894x over previous
//
#include <hip/hip_runtime.h>
#include <stdint.h>

// SimpleAttention v12: MFMA via the m92/m97-verified fragment recipe.
// Per (b,t): out[32i x 64d] = P[32i x 64j] * C[64j x 64d].
// A = P staged [i][j] bf16; B = C^T staged [d][j] bf16; lane l reads 8
// consecutive j at row (l&15), k-block (l>>4) via ds_read_b128 — identical
// pattern for A and B, so internal k-permutations cancel. C/D mapping
// (verified): col = lane&15 (d), row = (lane>>4)*4 + reg (i).

typedef unsigned int uint_t;
typedef float  f32x4   __attribute__((ext_vector_type(4)));
typedef short  short8v __attribute__((ext_vector_type(8)));

constexpr int Bq = 16, Cq = 3072, Tq = 2048;
constexpr int TT = 32, TILES = 64, NBLK = Bq * TILES;   // 1024 blocks
constexpr size_t ATT_OFF = (size_t)Bq * 2048 * Tq;
constexpr int TBS = 4224;                 // per-t staging block stride (bytes): 4096 data + 128 skew room
constexpr int LDS_BYTES = 135168;         // 32*TBS == 1024*33*4 (output transpose buffer, unioned)

__global__ __launch_bounds__(1024, 1) void attn_v12(const float* __restrict__ x,
                                                    const float* __restrict__ xi,
                                                    float* __restrict__ out)
{
    __shared__ __align__(16) unsigned char smem[LDS_BYTES];
    unsigned short* LU = (unsigned short*)smem;
    uint_t*         LW = (uint_t*)smem;
    float*          LF = (float*)smem;

    const int tid  = (int)threadIdx.x;
    const int b    = (int)blockIdx.x >> 6;
    const int tile = (int)blockIdx.x & (TILES - 1);
    const int t0   = tile * TT;
    const int tl   = tid & 31;           // t for phase A / staging / stores
    const int slot = tid >> 5;           // 0..31: i (phase A, P-stage), d (C-stage, store)

    const float* xb  = x  + (size_t)b * Cq * Tq + t0 + tl;
    const float* xib = xi + (size_t)b * Cq * Tq + t0 + tl;

    // ---- phase A (v5-proven): softmax row i=slot; attn out; pack p -> pk ----
    uint_t pk[32];
    {
        const int i = slot;
        float p[64];
#pragma unroll
        for (int j = 0; j < 32; ++j) p[j]      = xb [(size_t)(i * 96 + j) * Tq];
#pragma unroll
        for (int j = 0; j < 32; ++j) p[j + 32] = xib[(size_t)(i * 96 + j) * Tq];
        float m = p[0];
#pragma unroll
        for (int j = 1; j < 64; ++j) m = fmaxf(m, p[j]);
        float s = 0.f;
#pragma unroll
        for (int j = 0; j < 64; ++j) { p[j] = __expf(p[j] - m); s += p[j]; }
        const float inv = 1.f / s;
#pragma unroll
        for (int j = 0; j < 64; ++j) p[j] *= inv;

        float* ao = out + ATT_OFF + ((size_t)(b * 32 + i) * 32) * Tq + t0 + tl;
#pragma unroll
        for (int j = 0; j < 32; ++j) {
            float v = p[j] + ((j == i) ? 0.f : p[j + 32]);
            __builtin_nontemporal_store(v, &ao[(size_t)j * Tq]);
        }
#pragma unroll
        for (int k = 0; k < 32; ++k) {
            uint_t b0 = __float_as_uint(p[2 * k]);
            uint_t b1 = __float_as_uint(p[2 * k + 1]);
            uint_t lo = (b0 + 0x7fffu + ((b0 >> 16) & 1u)) >> 16;
            uint_t hi = (b1 + 0x7fffu + ((b1 >> 16) & 1u)) >> 16;
            pk[k] = lo | (hi << 16);
        }
    }

    // staging-side constants (row = slot)
    const int fw  = ((slot >> 2) & 3) ^ (slot & 3);      // kb-XOR swizzle for this row
    const int TBw = tl * TBS + (tl & 7) * 16;            // t-block byte base (staging)

    // mfma-side constants
    const int l   = tid & 63;
    const int wv  = tid >> 6;                            // wave 0..15 owns t = 2wv, 2wv+1
    const int frd = ((l >> 2) & 3) ^ (l & 3);            // row-XOR as lane function (row&15 = l&15)
    const int kbr = (((l >> 4) ^ frd) & 3) * 16;         // swizzled kb byte offset for reads
    const int rA  = (l & 15) * 64;                       // row-byte for s=0 / dt=0

#pragma unroll
    for (int dh = 0; dh < 2; ++dh) {
        f32x4 acc[2][2][2];                              // [q][s(i-tile)][dt(d-tile)]
#pragma unroll
        for (int q = 0; q < 2; ++q)
#pragma unroll
            for (int s = 0; s < 2; ++s)
#pragma unroll
                for (int dt = 0; dt < 2; ++dt) acc[q][s][dt] = (f32x4)(0.f);

#pragma unroll
        for (int jh = 0; jh < 2; ++jh) {
            // ---- stage P chunk: row i=slot, 16 dword writes (j-pairs), t=tl ----
#pragma unroll
            for (int m = 0; m < 16; ++m) {
                const int kbx  = (m >> 2) ^ fw;          // jl=2m -> kb = jl>>3 = m>>2
                const int byte = TBw + slot * 64 + kbx * 16 + ((2 * m) & 7) * 2;
                LW[byte >> 2] = pk[jh * 16 + m];
            }
            // ---- stage C chunk: row d=slot, 32 scalar j-loads -> bf16, t=tl ----
            {
                const float* src = (jh == 0) ? x : xi;
                const float* sp  = src + (size_t)b * Cq * Tq
                                 + (size_t)(32 + dh * 32 + slot) * Tq + t0 + tl;
#pragma unroll 8
                for (int kk = 0; kk < 32; ++kk) {
                    const float v = sp[(size_t)kk * 96 * Tq];
                    const uint_t bb = __float_as_uint(v);
                    const unsigned short h =
                        (unsigned short)((bb + 0x7fffu + ((bb >> 16) & 1u)) >> 16);
                    const int kbx  = (kk >> 3) ^ fw;
                    const int byte = TBw + 2048 + slot * 64 + kbx * 16 + (kk & 7) * 2;
                    LU[byte >> 1] = h;
                }
            }
            __syncthreads();                             // chunks staged

            // ---- MFMA: wave wv, t = 2wv+q; 4 tiles per t ----
#pragma unroll
            for (int q = 0; q < 2; ++q) {
                const int tloc = 2 * wv + q;
                const int base = tloc * TBS + (tloc & 7) * 16;
                const short8v A0 = *(const short8v*)(smem + base        + rA + kbr);
                const short8v A1 = *(const short8v*)(smem + base + 1024 + rA + kbr);
                const short8v B0 = *(const short8v*)(smem + base + 2048 + rA + kbr);
                const short8v B1 = *(const short8v*)(smem + base + 3072 + rA + kbr);
                acc[q][0][0] = __builtin_amdgcn_mfma_f32_16x16x32_bf16(A0, B0, acc[q][0][0], 0, 0, 0);
                acc[q][0][1] = __builtin_amdgcn_mfma_f32_16x16x32_bf16(A0, B1, acc[q][0][1], 0, 0, 0);
                acc[q][1][0] = __builtin_amdgcn_mfma_f32_16x16x32_bf16(A1, B0, acc[q][1][0], 0, 0, 0);
                acc[q][1][1] = __builtin_amdgcn_mfma_f32_16x16x32_bf16(A1, B1, acc[q][1][1], 0, 0, 0);
            }
            __syncthreads();                             // frag reads done before next stage
        }

        // ---- dump dh-half: acc -> olds [i*32+d][33] f32 -> full-line stores ----
#pragma unroll
        for (int q = 0; q < 2; ++q)
#pragma unroll
            for (int s = 0; s < 2; ++s)
#pragma unroll
                for (int dt = 0; dt < 2; ++dt)
#pragma unroll
                    for (int ri = 0; ri < 4; ++ri) {
                        const int ii = s * 16 + (l >> 4) * 4 + ri;
                        const int dl = dt * 16 + (l & 15);
                        LF[(ii * 32 + dl) * 33 + 2 * wv + q] = acc[q][s][dt][ri];
                    }
        __syncthreads();
        {
            float* ob = out + (size_t)b * 2048 * Tq + t0 + tl;
#pragma unroll 8
            for (int kk = 0; kk < 32; ++kk) {
                const int ch = kk * 64 + dh * 32 + slot;      // i=kk, d=dh*32+slot
                __builtin_nontemporal_store(LF[(kk * 32 + slot) * 33 + tl],
                                            &ob[(size_t)ch * Tq]);
            }
        }
        __syncthreads();                                 // olds region reused by next dh
    }
}

extern "C" void kernel_launch(void* const* d_in, const int* in_sizes, int n_in,
                              void* d_out, int out_size, void* d_ws, size_t ws_size,
                              hipStream_t stream) {
    const float* x  = (const float*)d_in[0];
    const float* xi = (const float*)d_in[1];
    float* out = (float*)d_out;
    attn_v12<<<dim3(NBLK), dim3(1024), 0, stream>>>(x, xi, out);
}

// Round 13
// 258.600 us; speedup vs baseline: 4.0819x; 1.0471x over previous
//
#include <hip/hip_runtime.h>
#include <stdint.h>

// SimpleAttention v13: v12 MFMA structure + register ping-pong prefetch of the
// ctx staging loads (chunk c+1 issued under chunk c's MFMA/dump), packed
// staging writes (b32/b64). Index math identical to v12 (verified).

typedef unsigned int uint_t;
typedef float  f32x4   __attribute__((ext_vector_type(4)));
typedef short  short8v __attribute__((ext_vector_type(8)));

constexpr int Bq = 16, Cq = 3072, Tq = 2048;
constexpr int TT = 32, TILES = 64, NBLK = Bq * TILES;   // 1024 blocks
constexpr size_t ATT_OFF = (size_t)Bq * 2048 * Tq;
constexpr int TBS = 4224;                 // per-t staging block stride (bytes)
constexpr int LDS_BYTES = 135168;         // 32*TBS == 1024*33*4 (unioned with olds)

__global__ __launch_bounds__(1024, 1) void attn_v13(const float* __restrict__ x,
                                                    const float* __restrict__ xi,
                                                    float* __restrict__ out)
{
    __shared__ __align__(16) unsigned char smem[LDS_BYTES];
    uint_t*    LW = (uint_t*)smem;
    uint64_t*  LQ = (uint64_t*)smem;
    float*     LF = (float*)smem;

    const int tid  = (int)threadIdx.x;
    const int b    = (int)blockIdx.x >> 6;
    const int tile = (int)blockIdx.x & (TILES - 1);
    const int t0   = tile * TT;
    const int tl   = tid & 31;           // t for phase A / staging / stores
    const int slot = tid >> 5;           // 0..31: i (phase A, P-stage), d (C-stage, store)

    const float* xb  = x  + (size_t)b * Cq * Tq + t0 + tl;
    const float* xib = xi + (size_t)b * Cq * Tq + t0 + tl;

    // ---- phase A: softmax row i=slot; attn out; pack p -> pk ----
    uint_t pk[32];
    float  cre[32];                      // ctx prefetch buffer (one chunk ahead)

    auto issue = [&](int c) {            // c = dh*2 + jh, literal-called only
        const int dh = c >> 1, jh = c & 1;
        const float* src = (jh == 0) ? x : xi;
        const float* sp  = src + (size_t)b * Cq * Tq
                         + (size_t)(32 + dh * 32 + slot) * Tq + t0 + tl;
#pragma unroll
        for (int kk = 0; kk < 32; ++kk) cre[kk] = sp[(size_t)kk * 96 * Tq];
    };

    {
        const int i = slot;
        float p[64];
#pragma unroll
        for (int j = 0; j < 32; ++j) p[j]      = xb [(size_t)(i * 96 + j) * Tq];
#pragma unroll
        for (int j = 0; j < 32; ++j) p[j + 32] = xib[(size_t)(i * 96 + j) * Tq];
        float m = p[0];
#pragma unroll
        for (int j = 1; j < 64; ++j) m = fmaxf(m, p[j]);
        float s = 0.f;
#pragma unroll
        for (int j = 0; j < 64; ++j) { p[j] = __expf(p[j] - m); s += p[j]; }
        const float inv = 1.f / s;
#pragma unroll
        for (int j = 0; j < 64; ++j) p[j] *= inv;

        float* ao = out + ATT_OFF + ((size_t)(b * 32 + i) * 32) * Tq + t0 + tl;
#pragma unroll
        for (int j = 0; j < 32; ++j) {
            float v = p[j] + ((j == i) ? 0.f : p[j + 32]);
            __builtin_nontemporal_store(v, &ao[(size_t)j * Tq]);
        }
#pragma unroll
        for (int k = 0; k < 32; ++k) {
            uint_t b0 = __float_as_uint(p[2 * k]);
            uint_t b1 = __float_as_uint(p[2 * k + 1]);
            uint_t lo = (b0 + 0x7fffu + ((b0 >> 16) & 1u)) >> 16;
            uint_t hi = (b1 + 0x7fffu + ((b1 >> 16) & 1u)) >> 16;
            pk[k] = lo | (hi << 16);
        }
    }
    issue(0);                            // chunk-0 ctx loads fly from here

    // staging-side constants (row = slot)
    const int fw  = ((slot >> 2) & 3) ^ (slot & 3);      // kb-XOR swizzle
    const int TBw = tl * TBS + (tl & 7) * 16;            // t-block byte base

    // mfma-side constants
    const int l   = tid & 63;
    const int wv  = tid >> 6;                            // wave owns t = 2wv, 2wv+1
    const int frd = ((l >> 2) & 3) ^ (l & 3);
    const int kbr = (((l >> 4) ^ frd) & 3) * 16;
    const int rA  = (l & 15) * 64;

    // staging writers (chunk index only affects pk half via jh)
    auto stageP = [&](int jh) {
#pragma unroll
        for (int m = 0; m < 16; m += 2) {                // pairs (m, m+1) share kb
            const int kbx  = (m >> 2) ^ fw;
            const int byte = TBw + slot * 64 + kbx * 16 + ((2 * m) & 7) * 2;
            uint64_t w = (uint64_t)pk[jh * 16 + m] |
                         ((uint64_t)pk[jh * 16 + m + 1] << 32);
            LQ[byte >> 3] = w;
        }
    };
    auto stageC = [&]() {                                 // consumes cre[]
#pragma unroll
        for (int kk = 0; kk < 32; kk += 2) {
            uint_t b0 = __float_as_uint(cre[kk]);
            uint_t b1 = __float_as_uint(cre[kk + 1]);
            uint_t h0 = (b0 + 0x7fffu + ((b0 >> 16) & 1u)) >> 16;
            uint_t h1 = (b1 + 0x7fffu + ((b1 >> 16) & 1u)) >> 16;
            const int kbx  = (kk >> 3) ^ fw;
            const int byte = TBw + 2048 + slot * 64 + kbx * 16 + (kk & 7) * 2;
            LW[byte >> 2] = h0 | (h1 << 16);
        }
    };

    f32x4 acc[2][2][2];                                  // [q][s][dt]
    auto accClr = [&]() {
#pragma unroll
        for (int q = 0; q < 2; ++q)
#pragma unroll
            for (int s = 0; s < 2; ++s)
#pragma unroll
                for (int dt = 0; dt < 2; ++dt) acc[q][s][dt] = (f32x4)(0.f);
    };
    auto mfmaChunk = [&]() {
#pragma unroll
        for (int q = 0; q < 2; ++q) {
            const int tloc = 2 * wv + q;
            const int base = tloc * TBS + (tloc & 7) * 16;
            const short8v A0 = *(const short8v*)(smem + base        + rA + kbr);
            const short8v A1 = *(const short8v*)(smem + base + 1024 + rA + kbr);
            const short8v B0 = *(const short8v*)(smem + base + 2048 + rA + kbr);
            const short8v B1 = *(const short8v*)(smem + base + 3072 + rA + kbr);
            acc[q][0][0] = __builtin_amdgcn_mfma_f32_16x16x32_bf16(A0, B0, acc[q][0][0], 0, 0, 0);
            acc[q][0][1] = __builtin_amdgcn_mfma_f32_16x16x32_bf16(A0, B1, acc[q][0][1], 0, 0, 0);
            acc[q][1][0] = __builtin_amdgcn_mfma_f32_16x16x32_bf16(A1, B0, acc[q][1][0], 0, 0, 0);
            acc[q][1][1] = __builtin_amdgcn_mfma_f32_16x16x32_bf16(A1, B1, acc[q][1][1], 0, 0, 0);
        }
    };
    auto dump = [&](int dh) {                            // olds transpose + stores
#pragma unroll
        for (int q = 0; q < 2; ++q)
#pragma unroll
            for (int s = 0; s < 2; ++s)
#pragma unroll
                for (int dt = 0; dt < 2; ++dt)
#pragma unroll
                    for (int ri = 0; ri < 4; ++ri) {
                        const int ii = s * 16 + (l >> 4) * 4 + ri;
                        const int dl = dt * 16 + (l & 15);
                        LF[(ii * 32 + dl) * 33 + 2 * wv + q] = acc[q][s][dt][ri];
                    }
        __syncthreads();
        float* ob = out + (size_t)b * 2048 * Tq + t0 + tl;
#pragma unroll 8
        for (int kk = 0; kk < 32; ++kk) {
            const int ch = kk * 64 + dh * 32 + slot;
            __builtin_nontemporal_store(LF[(kk * 32 + slot) * 33 + tl],
                                        &ob[(size_t)ch * Tq]);
        }
        __syncthreads();                                 // region reused next
    };

    // ---- pipelined chunks: c = dh*2 + jh ----
    accClr();
    // c = 0 (dh0, jh0)
    stageP(0); stageC();
    __syncthreads();
    issue(1);
    mfmaChunk();
    __syncthreads();
    // c = 1 (dh0, jh1)
    stageP(1); stageC();
    __syncthreads();
    issue(2);
    mfmaChunk();
    __syncthreads();
    dump(0);
    accClr();
    // c = 2 (dh1, jh0)
    stageP(0); stageC();
    __syncthreads();
    issue(3);
    mfmaChunk();
    __syncthreads();
    // c = 3 (dh1, jh1)
    stageP(1); stageC();
    __syncthreads();
    mfmaChunk();
    __syncthreads();
    dump(1);
}

extern "C" void kernel_launch(void* const* d_in, const int* in_sizes, int n_in,
                              void* d_out, int out_size, void* d_ws, size_t ws_size,
                              hipStream_t stream) {
    const float* x  = (const float*)d_in[0];
    const float* xi = (const float*)d_in[1];
    float* out = (float*)d_out;
    attn_v13<<<dim3(NBLK), dim3(1024), 0, stream>>>(x, xi, out);
}